// Round 1
// baseline (182.728 us; speedup 1.0000x reference)
//
#include <hip/hip_runtime.h>

typedef __attribute__((ext_vector_type(8))) __bf16 bf16x8;
typedef __attribute__((ext_vector_type(4))) float f32x4;

#define B_ 16
#define S_ 1024
#define D_ 1024
#define R_ 128

// proj [D][R] fp32  ->  projT [R][D] bf16  (transpose + cast, LDS tiled)
__global__ __launch_bounds__(256) void k_transpose(const float* __restrict__ proj,
                                                   __bf16* __restrict__ projT) {
    __shared__ __bf16 tile[64][66];  // +2 pad: odd dword stride breaks bank aliasing
    const int k0 = blockIdx.x * 64;
    const int r0 = blockIdx.y * 64;
#pragma unroll
    for (int it = 0; it < 16; ++it) {
        int idx = it * 256 + threadIdx.x;
        int kk = idx >> 6, rr = idx & 63;
        tile[kk][rr] = (__bf16)proj[(size_t)(k0 + kk) * R_ + (r0 + rr)];
    }
    __syncthreads();
#pragma unroll
    for (int it = 0; it < 16; ++it) {
        int idx = it * 256 + threadIdx.x;
        int rr = idx >> 6, kk = idx & 63;
        projT[(size_t)(r0 + rr) * D_ + (k0 + kk)] = tile[kk][rr];
    }
}

// t = batch @ proj  (bf16 MFMA, fp32 accum), also writes bf16 t and sq_norms.
// Block: 256 thr = 4 waves; each wave: 16 rows x full R=128 (8 n-tiles), K-loop 1024.
__global__ __launch_bounds__(256) void k_proj(const float* __restrict__ batch,
                                              const __bf16* __restrict__ projT,
                                              __bf16* __restrict__ t,
                                              float* __restrict__ sqn) {
    const int wave = threadIdx.x >> 6;
    const int lane = threadIdx.x & 63;
    const int ln = lane & 15;   // A-row / D-col selector
    const int q  = lane >> 4;   // quad: k-chunk selector (input), row-group (output)
    const int m0 = blockIdx.x * 64 + wave * 16;
    const float* arow = batch + (size_t)(m0 + ln) * D_;

    f32x4 acc[8];
#pragma unroll
    for (int ni = 0; ni < 8; ++ni) acc[ni] = f32x4{0.f, 0.f, 0.f, 0.f};

    for (int k0 = 0; k0 < D_; k0 += 32) {
        const int ka = k0 + q * 8;
        // A fragment: A[m=ln][k=ka..ka+7] from fp32 batch, packed to bf16
        float4 alo = *(const float4*)(arow + ka);
        float4 ahi = *(const float4*)(arow + ka + 4);
        bf16x8 af;
        af[0] = (__bf16)alo.x; af[1] = (__bf16)alo.y;
        af[2] = (__bf16)alo.z; af[3] = (__bf16)alo.w;
        af[4] = (__bf16)ahi.x; af[5] = (__bf16)ahi.y;
        af[6] = (__bf16)ahi.z; af[7] = (__bf16)ahi.w;
#pragma unroll
        for (int ni = 0; ni < 8; ++ni) {
            // B fragment: B[k][n] = proj[k][n] = projT[n][k], contiguous 16 B
            bf16x8 bf = *(const bf16x8*)(projT + (size_t)(ni * 16 + ln) * D_ + ka);
            acc[ni] = __builtin_amdgcn_mfma_f32_16x16x32_bf16(af, bf, acc[ni], 0, 0, 0);
        }
    }

    // D mapping: col = ni*16 + ln, row = q*4 + r (within this wave's 16-row tile)
    float sq[4] = {0.f, 0.f, 0.f, 0.f};
#pragma unroll
    for (int ni = 0; ni < 8; ++ni) {
#pragma unroll
        for (int r = 0; r < 4; ++r) {
            __bf16 v = (__bf16)acc[ni][r];
            t[(size_t)(m0 + q * 4 + r) * R_ + ni * 16 + ln] = v;
            float f = (float)v;
            sq[r] += f * f;  // sq_norm from the *rounded* t for diag consistency
        }
    }
    // reduce across the 16 lanes (ln dim) sharing each row
#pragma unroll
    for (int r = 0; r < 4; ++r) {
#pragma unroll
        for (int off = 1; off < 16; off <<= 1)
            sq[r] += __shfl_xor(sq[r], off, 64);
    }
    if (ln == 0) {
#pragma unroll
        for (int r = 0; r < 4; ++r) sqn[m0 + q * 4 + r] = sq[r];
    }
}

// Per batch: cross = t @ t^T; out = max(0, sqn_i + sqn_j - 2*cross).
// Grid (8,8,16); block 256 thr = 4 waves in 2x2; each wave a 64x64 tile; K=128.
__global__ __launch_bounds__(256) void k_gram(const __bf16* __restrict__ t,
                                              const float* __restrict__ sqn,
                                              float* __restrict__ out) {
    const int b = blockIdx.z;
    const int wave = threadIdx.x >> 6;
    const int lane = threadIdx.x & 63;
    const int ln = lane & 15;
    const int q  = lane >> 4;
    const int wi = wave >> 1, wj = wave & 1;
    const int i0 = blockIdx.y * 128 + wi * 64;
    const int j0 = blockIdx.x * 128 + wj * 64;
    const __bf16* tb = t + (size_t)b * S_ * R_;
    const float* sqb = sqn + (size_t)b * S_;

    f32x4 acc[4][4];
#pragma unroll
    for (int mi = 0; mi < 4; ++mi)
#pragma unroll
        for (int ni = 0; ni < 4; ++ni) acc[mi][ni] = f32x4{0.f, 0.f, 0.f, 0.f};

#pragma unroll
    for (int k0 = 0; k0 < R_; k0 += 32) {
        const int ka = k0 + q * 8;
        bf16x8 af[4], bfm[4];
#pragma unroll
        for (int mi = 0; mi < 4; ++mi)
            af[mi] = *(const bf16x8*)(tb + (size_t)(i0 + mi * 16 + ln) * R_ + ka);
#pragma unroll
        for (int ni = 0; ni < 4; ++ni)
            bfm[ni] = *(const bf16x8*)(tb + (size_t)(j0 + ni * 16 + ln) * R_ + ka);
#pragma unroll
        for (int mi = 0; mi < 4; ++mi)
#pragma unroll
            for (int ni = 0; ni < 4; ++ni)
                acc[mi][ni] = __builtin_amdgcn_mfma_f32_16x16x32_bf16(
                    af[mi], bfm[ni], acc[mi][ni], 0, 0, 0);
    }

    float sqj[4];
#pragma unroll
    for (int ni = 0; ni < 4; ++ni) sqj[ni] = sqb[j0 + ni * 16 + ln];

    float* outb = out + (size_t)b * S_ * S_;
#pragma unroll
    for (int mi = 0; mi < 4; ++mi) {
#pragma unroll
        for (int r = 0; r < 4; ++r) {
            const int i = i0 + mi * 16 + q * 4 + r;
            const float si = sqb[i];
            float* orow = outb + (size_t)i * S_ + j0;
#pragma unroll
            for (int ni = 0; ni < 4; ++ni) {
                float v = si + sqj[ni] - 2.f * acc[mi][ni][r];
                orow[ni * 16 + ln] = fmaxf(v, 0.f);
            }
        }
    }
}

extern "C" void kernel_launch(void* const* d_in, const int* in_sizes, int n_in,
                              void* d_out, int out_size, void* d_ws, size_t ws_size,
                              hipStream_t stream) {
    const float* batch = (const float*)d_in[0];  // [16,1024,1024] fp32
    const float* proj  = (const float*)d_in[1];  // [1024,128] fp32
    float* out = (float*)d_out;                  // [16,1024,1024] fp32

    char* ws = (char*)d_ws;
    __bf16* t     = (__bf16*)ws;                                   // 16384x128 bf16 = 4 MB
    __bf16* projT = (__bf16*)(ws + (size_t)B_ * S_ * R_ * 2);      // 128x1024 bf16 = 256 KB
    float*  sqn   = (float*)(ws + (size_t)B_ * S_ * R_ * 2
                                + (size_t)R_ * D_ * 2);            // 16384 fp32 = 64 KB

    k_transpose<<<dim3(D_ / 64, R_ / 64), 256, 0, stream>>>(proj, projT);
    k_proj<<<dim3((B_ * S_) / 64), 256, 0, stream>>>(batch, projT, t, sqn);
    k_gram<<<dim3(S_ / 128, S_ / 128, B_), 256, 0, stream>>>(t, sqn, out);
}

// Round 2
// 156.764 us; speedup vs baseline: 1.1656x; 1.1656x over previous
//
#include <hip/hip_runtime.h>

typedef __attribute__((ext_vector_type(8))) __bf16 bf16x8;
typedef __attribute__((ext_vector_type(4))) float f32x4;

#define B_ 16
#define S_ 1024
#define D_ 1024
#define R_ 128

// proj [D][R] fp32  ->  projT [R][D] bf16  (transpose + cast, LDS tiled)
__global__ __launch_bounds__(256) void k_transpose(const float* __restrict__ proj,
                                                   __bf16* __restrict__ projT) {
    __shared__ __bf16 tile[64][66];  // +2 pad: odd dword stride breaks bank aliasing
    const int k0 = blockIdx.x * 64;
    const int r0 = blockIdx.y * 64;
#pragma unroll
    for (int it = 0; it < 16; ++it) {
        int idx = it * 256 + threadIdx.x;
        int kk = idx >> 6, rr = idx & 63;
        tile[kk][rr] = (__bf16)proj[(size_t)(k0 + kk) * R_ + (r0 + rr)];
    }
    __syncthreads();
#pragma unroll
    for (int it = 0; it < 16; ++it) {
        int idx = it * 256 + threadIdx.x;
        int rr = idx >> 6, kk = idx & 63;
        projT[(size_t)(r0 + rr) * D_ + (k0 + kk)] = tile[kk][rr];
    }
}

// t = batch @ proj (bf16 MFMA, fp32 accum) + bf16 t + sq_norms.
// v2: K-split for occupancy. Block = 16 rows; 4 waves each own a K=256 slice;
// LDS reduction of partial accumulators. Grid 1024 blocks -> 4 blocks/CU,
// 16 waves/CU (was 4).
__global__ __launch_bounds__(256, 4) void k_proj(const float* __restrict__ batch,
                                                 const __bf16* __restrict__ projT,
                                                 __bf16* __restrict__ t,
                                                 float* __restrict__ sqn) {
    const int wave = threadIdx.x >> 6;
    const int lane = threadIdx.x & 63;
    const int ln = lane & 15;   // A-row / D-col selector
    const int q  = lane >> 4;   // quad: k-chunk selector (input), row-group (output)
    const int m0 = blockIdx.x * 16;
    const int kbase = wave * 256;   // this wave's K slice
    const float* arow = batch + (size_t)(m0 + ln) * D_ + kbase;

    f32x4 acc[8];
#pragma unroll
    for (int ni = 0; ni < 8; ++ni) acc[ni] = f32x4{0.f, 0.f, 0.f, 0.f};

#pragma unroll 4
    for (int k0 = 0; k0 < 256; k0 += 32) {
        const int ka = k0 + q * 8;
        // A fragment: A[m=ln][k=ka..ka+7] from fp32 batch, packed to bf16
        float4 alo = *(const float4*)(arow + ka);
        float4 ahi = *(const float4*)(arow + ka + 4);
        bf16x8 af;
        af[0] = (__bf16)alo.x; af[1] = (__bf16)alo.y;
        af[2] = (__bf16)alo.z; af[3] = (__bf16)alo.w;
        af[4] = (__bf16)ahi.x; af[5] = (__bf16)ahi.y;
        af[6] = (__bf16)ahi.z; af[7] = (__bf16)ahi.w;
#pragma unroll
        for (int ni = 0; ni < 8; ++ni) {
            // B fragment: B[k][n] = projT[n][k], contiguous 16 B
            bf16x8 bf = *(const bf16x8*)(projT + (size_t)(ni * 16 + ln) * D_ + kbase + ka);
            acc[ni] = __builtin_amdgcn_mfma_f32_16x16x32_bf16(af, bf, acc[ni], 0, 0, 0);
        }
    }

    // Cross-wave K reduction through LDS. red[w][ni][lane] is one f32x4 (16 B
    // per lane, lane-sequential -> conflict-free).
    __shared__ f32x4 red[4][8][64];
    __shared__ float sqpart[4][16];
#pragma unroll
    for (int ni = 0; ni < 8; ++ni) red[wave][ni][lane] = acc[ni];
    __syncthreads();

    // Each wave finalizes 2 ni-tiles (cols 32*wave .. 32*wave+31).
    float sq[4] = {0.f, 0.f, 0.f, 0.f};
#pragma unroll
    for (int p = 0; p < 2; ++p) {
        const int ni = wave * 2 + p;
        f32x4 v = red[0][ni][lane];
#pragma unroll
        for (int w = 1; w < 4; ++w) {
            f32x4 u = red[w][ni][lane];
            v[0] += u[0]; v[1] += u[1]; v[2] += u[2]; v[3] += u[3];
        }
        // D mapping: col = ni*16 + ln, row = q*4 + r
#pragma unroll
        for (int r = 0; r < 4; ++r) {
            __bf16 h = (__bf16)v[r];
            t[(size_t)(m0 + q * 4 + r) * R_ + ni * 16 + ln] = h;
            float f = (float)h;
            sq[r] += f * f;  // sq_norm from *rounded* t: keeps diagonal exact vs gram
        }
    }
    // reduce sq across the 16 lanes (ln) sharing each row -> partial over 32 cols
#pragma unroll
    for (int r = 0; r < 4; ++r) {
#pragma unroll
        for (int off = 1; off < 16; off <<= 1)
            sq[r] += __shfl_xor(sq[r], off, 64);
    }
    if (ln == 0) {
#pragma unroll
        for (int r = 0; r < 4; ++r) sqpart[wave][q * 4 + r] = sq[r];
    }
    __syncthreads();
    if (threadIdx.x < 16) {
        float s = sqpart[0][threadIdx.x] + sqpart[1][threadIdx.x] +
                  sqpart[2][threadIdx.x] + sqpart[3][threadIdx.x];
        sqn[m0 + threadIdx.x] = s;
    }
}

// Per batch: cross = t @ t^T; out = max(0, sqn_i + sqn_j - 2*cross).
// Grid (8,8,16); block 256 thr = 4 waves in 2x2; each wave a 64x64 tile; K=128.
__global__ __launch_bounds__(256) void k_gram(const __bf16* __restrict__ t,
                                              const float* __restrict__ sqn,
                                              float* __restrict__ out) {
    const int b = blockIdx.z;
    const int wave = threadIdx.x >> 6;
    const int lane = threadIdx.x & 63;
    const int ln = lane & 15;
    const int q  = lane >> 4;
    const int wi = wave >> 1, wj = wave & 1;
    const int i0 = blockIdx.y * 128 + wi * 64;
    const int j0 = blockIdx.x * 128 + wj * 64;
    const __bf16* tb = t + (size_t)b * S_ * R_;
    const float* sqb = sqn + (size_t)b * S_;

    f32x4 acc[4][4];
#pragma unroll
    for (int mi = 0; mi < 4; ++mi)
#pragma unroll
        for (int ni = 0; ni < 4; ++ni) acc[mi][ni] = f32x4{0.f, 0.f, 0.f, 0.f};

#pragma unroll
    for (int k0 = 0; k0 < R_; k0 += 32) {
        const int ka = k0 + q * 8;
        bf16x8 af[4], bfm[4];
#pragma unroll
        for (int mi = 0; mi < 4; ++mi)
            af[mi] = *(const bf16x8*)(tb + (size_t)(i0 + mi * 16 + ln) * R_ + ka);
#pragma unroll
        for (int ni = 0; ni < 4; ++ni)
            bfm[ni] = *(const bf16x8*)(tb + (size_t)(j0 + ni * 16 + ln) * R_ + ka);
#pragma unroll
        for (int mi = 0; mi < 4; ++mi)
#pragma unroll
            for (int ni = 0; ni < 4; ++ni)
                acc[mi][ni] = __builtin_amdgcn_mfma_f32_16x16x32_bf16(
                    af[mi], bfm[ni], acc[mi][ni], 0, 0, 0);
    }

    float sqj[4];
#pragma unroll
    for (int ni = 0; ni < 4; ++ni) sqj[ni] = sqb[j0 + ni * 16 + ln];

    float* outb = out + (size_t)b * S_ * S_;
#pragma unroll
    for (int mi = 0; mi < 4; ++mi) {
#pragma unroll
        for (int r = 0; r < 4; ++r) {
            const int i = i0 + mi * 16 + q * 4 + r;
            const float si = sqb[i];
            float* orow = outb + (size_t)i * S_ + j0;
#pragma unroll
            for (int ni = 0; ni < 4; ++ni) {
                float v = si + sqj[ni] - 2.f * acc[mi][ni][r];
                orow[ni * 16 + ln] = fmaxf(v, 0.f);
            }
        }
    }
}

extern "C" void kernel_launch(void* const* d_in, const int* in_sizes, int n_in,
                              void* d_out, int out_size, void* d_ws, size_t ws_size,
                              hipStream_t stream) {
    const float* batch = (const float*)d_in[0];  // [16,1024,1024] fp32
    const float* proj  = (const float*)d_in[1];  // [1024,128] fp32
    float* out = (float*)d_out;                  // [16,1024,1024] fp32

    char* ws = (char*)d_ws;
    __bf16* t     = (__bf16*)ws;                                   // 16384x128 bf16 = 4 MB
    __bf16* projT = (__bf16*)(ws + (size_t)B_ * S_ * R_ * 2);      // 128x1024 bf16 = 256 KB
    float*  sqn   = (float*)(ws + (size_t)B_ * S_ * R_ * 2
                                + (size_t)R_ * D_ * 2);            // 16384 fp32 = 64 KB

    k_transpose<<<dim3(D_ / 64, R_ / 64), 256, 0, stream>>>(proj, projT);
    k_proj<<<dim3((B_ * S_) / 16), 256, 0, stream>>>(batch, projT, t, sqn);
    k_gram<<<dim3(S_ / 128, S_ / 128, B_), 256, 0, stream>>>(t, sqn, out);
}